// Round 2
// baseline (216.747 us; speedup 1.0000x reference)
//
#include <hip/hip_runtime.h>

#define S49 49
#define D128 128
#define NH 4

typedef __attribute__((ext_vector_type(8))) short short8;
typedef __attribute__((ext_vector_type(4))) float f32x4;

#define HS_STRIDE 136   // bf16 elems per row for hs_s/q_s/k_s (272B: 16B-aligned rows, 2-way-max frag banks)
#define VT_STRIDE 72    // vt rows (144B)
#define SP_STRIDE 72    // score/prob rows (144B)

__device__ __forceinline__ unsigned short f2b(float x){
  unsigned u = __builtin_bit_cast(unsigned, x);
  return (unsigned short)((u + 0x7fffu + ((u>>16)&1u)) >> 16);   // RNE
}
__device__ __forceinline__ float b2f(unsigned short u){
  return __builtin_bit_cast(float, ((unsigned)u)<<16);
}
__device__ __forceinline__ unsigned pack2(float a, float b){
  return (unsigned)f2b(a) | ((unsigned)f2b(b)<<16);
}

// ---- K0: transpose weights to Wt[mat][n][k] bf16 in workspace ----
__global__ void prep_wt(const float* __restrict__ Wq, const float* __restrict__ Wk,
                        const float* __restrict__ Wv, unsigned short* __restrict__ wt){
  int e = blockIdx.x*256 + threadIdx.x;
  if (e >= 3*128*128) return;
  int mat = e >> 14, rem = e & 16383, n = rem >> 7, k = rem & 127;
  const float* W = (mat==0) ? Wq : ((mat==1) ? Wk : Wv);
  wt[e] = f2b(W[k*128 + n]);
}

// ---- main fused kernel: one block per window ----
__global__ __launch_bounds__(256, 2) void swin_attn(
    const float* __restrict__ hs, const float* __restrict__ mask,
    const float* __restrict__ bq, const float* __restrict__ bk,
    const float* __restrict__ bv, const float* __restrict__ bt,
    const unsigned short* __restrict__ wt, float* __restrict__ out, int nW){

  __shared__ __align__(16) unsigned short hs_s[S49*HS_STRIDE];  // later reused as score/prob buffer
  __shared__ __align__(16) unsigned short q_s [S49*HS_STRIDE];
  __shared__ __align__(16) unsigned short k_s [S49*HS_STRIDE];
  __shared__ __align__(16) unsigned short vt_s[128*VT_STRIDE];
  unsigned short* sp_s = hs_s;

  const int b = blockIdx.x;
  const int tid = threadIdx.x;
  const int wave = tid >> 6, lane = tid & 63;
  const int lg = lane >> 4, ln = lane & 15;

  // ---- stage hidden_states f32 -> bf16 LDS ----
  const float* hsb = hs + (size_t)b * (S49*D128);
  #pragma unroll
  for (int it = 0; it < 7; ++it) {
    int u = tid + it*256;                 // 1568 units of 4 f32
    if (u < S49*32) {
      int row = u >> 5, c = u & 31;
      float4 f = *(const float4*)(hsb + row*128 + c*4);
      uint2 o; o.x = pack2(f.x, f.y); o.y = pack2(f.z, f.w);
      *(uint2*)&hs_s[row*HS_STRIDE + c*4] = o;
    }
  }
  // zero vt padding cols 49..63 (K-pad for PV)
  for (int u = tid; u < 128*15; u += 256) {
    int r = u/15, c = 49 + (u - r*15);
    vt_s[r*VT_STRIDE + c] = 0;
  }
  __syncthreads();

  // ---- QKV projections (weights as A-operand; wave owns 32 output cols) ----
  {
    #pragma unroll
    for (int ntl = 0; ntl < 2; ++ntl) {
      const int ntb = wave*32 + ntl*16;
      short8 a[3][4];
      #pragma unroll
      for (int mat = 0; mat < 3; ++mat)
        #pragma unroll
        for (int ks = 0; ks < 4; ++ks)
          a[mat][ks] = *(const short8*)&wt[(mat<<14) + (ntb+ln)*128 + ks*32 + lg*8];
      float4 bias_q = *(const float4*)&bq[ntb + 4*lg];
      float4 bias_k = *(const float4*)&bk[ntb + 4*lg];
      float4 bias_v = *(const float4*)&bv[ntb + 4*lg];
      #pragma unroll
      for (int mt = 0; mt < 4; ++mt) {
        const int mb = (mt<3) ? mt*16 : 33;       // overlapping tiles cover rows 0..48
        short8 bh[4];
        #pragma unroll
        for (int ks = 0; ks < 4; ++ks)
          bh[ks] = *(const short8*)&hs_s[(mb+ln)*HS_STRIDE + ks*32 + lg*8];
        #pragma unroll
        for (int mat = 0; mat < 3; ++mat) {
          f32x4 acc = {0.f,0.f,0.f,0.f};
          #pragma unroll
          for (int ks = 0; ks < 4; ++ks)
            acc = __builtin_amdgcn_mfma_f32_16x16x32_bf16(a[mat][ks], bh[ks], acc, 0,0,0);
          // D is transposed: col(ln)=row m of output, rows(4*lg+r)=output col n
          const int m = mb + ln;
          const int nb = ntb + 4*lg;
          if (mat == 0) {
            uint2 o; o.x = pack2(acc[0]+bias_q.x, acc[1]+bias_q.y);
                     o.y = pack2(acc[2]+bias_q.z, acc[3]+bias_q.w);
            *(uint2*)&q_s[m*HS_STRIDE + nb] = o;
          } else if (mat == 1) {
            uint2 o; o.x = pack2(acc[0]+bias_k.x, acc[1]+bias_k.y);
                     o.y = pack2(acc[2]+bias_k.z, acc[3]+bias_k.w);
            *(uint2*)&k_s[m*HS_STRIDE + nb] = o;
          } else {
            vt_s[(nb+0)*VT_STRIDE + m] = f2b(acc[0]+bias_v.x);
            vt_s[(nb+1)*VT_STRIDE + m] = f2b(acc[1]+bias_v.y);
            vt_s[(nb+2)*VT_STRIDE + m] = f2b(acc[2]+bias_v.z);
            vt_s[(nb+3)*VT_STRIDE + m] = f2b(acc[3]+bias_v.w);
          }
        }
      }
    }
  }
  __syncthreads();

  const float scale = 0.17677669529663687f;   // 1/sqrt(32)
  const int w = b % nW;
  const int mbw = (wave<3) ? wave*16 : 33;

  #pragma unroll 1
  for (int h = 0; h < NH; ++h) {
    // ---- QK^T (wave = q row-tile) ----
    {
      short8 aq = *(const short8*)&q_s[(mbw+ln)*HS_STRIDE + h*32 + lg*8];
      #pragma unroll
      for (int nt = 0; nt < 4; ++nt) {
        const int nb = (nt<3) ? nt*16 : 33;
        short8 kb = *(const short8*)&k_s[(nb+ln)*HS_STRIDE + h*32 + lg*8];
        f32x4 acc = {0.f,0.f,0.f,0.f};
        acc = __builtin_amdgcn_mfma_f32_16x16x32_bf16(aq, kb, acc, 0,0,0);
        const int j = nb + ln, mr = mbw + 4*lg;
        sp_s[(mr+0)*SP_STRIDE + j] = f2b(acc[0]);
        sp_s[(mr+1)*SP_STRIDE + j] = f2b(acc[1]);
        sp_s[(mr+2)*SP_STRIDE + j] = f2b(acc[2]);
        sp_s[(mr+3)*SP_STRIDE + j] = f2b(acc[3]);
      }
    }
    if (h == 0) {  // zero K-pad cols 49..63 of prob buffer (disjoint from QK writes)
      for (int u = tid; u < S49*15; u += 256) {
        int r = u/15, c = 49 + (u - r*15);
        sp_s[r*SP_STRIDE + c] = 0;
      }
    }
    __syncthreads();

    // ---- softmax, one row per thread (scale + rel-pos bias + mask, fully unrolled) ----
    if (tid < S49) {
      const int i = tid;
      float sv[52];
      #pragma unroll
      for (int c = 0; c < 13; ++c) {
        uint2 p2 = *(const uint2*)&sp_s[i*SP_STRIDE + c*4];
        sv[c*4+0] = b2f((unsigned short)(p2.x & 0xffffu));
        sv[c*4+1] = b2f((unsigned short)(p2.x >> 16));
        sv[c*4+2] = b2f((unsigned short)(p2.y & 0xffffu));
        sv[c*4+3] = b2f((unsigned short)(p2.y >> 16));
      }
      const float* mrow = mask + ((size_t)w*S49 + i)*S49;
      const int ri = i/7, ci = i - ri*7;
      const int bbase = (ri*13 + ci + 84)*NH + h;
      #pragma unroll
      for (int j = 0; j < S49; ++j) {
        const int rj = j/7, cj = j - rj*7;
        sv[j] = sv[j]*scale + mrow[j] + bt[bbase - (rj*13+cj)*NH];
      }
      float mx = sv[0];
      #pragma unroll
      for (int j = 1; j < S49; ++j) mx = fmaxf(mx, sv[j]);
      float sum = 0.f;
      #pragma unroll
      for (int j = 0; j < S49; ++j) { float e = exp2f((sv[j]-mx)*1.44269504f); sv[j] = e; sum += e; }
      const float inv = 1.0f / sum;
      #pragma unroll
      for (int c = 0; c < 13; ++c) {
        float v0 = (c*4+0 < S49) ? sv[c*4+0]*inv : 0.f;
        float v1 = (c*4+1 < S49) ? sv[c*4+1]*inv : 0.f;
        float v2 = (c*4+2 < S49) ? sv[c*4+2]*inv : 0.f;
        float v3 = (c*4+3 < S49) ? sv[c*4+3]*inv : 0.f;
        uint2 o; o.x = pack2(v0,v1); o.y = pack2(v2,v3);
        *(uint2*)&sp_s[i*SP_STRIDE + c*4] = o;
      }
    }
    __syncthreads();

    // ---- P @ V ----
    {
      short8 ap0 = *(const short8*)&sp_s[(mbw+ln)*SP_STRIDE + lg*8];
      short8 ap1 = *(const short8*)&sp_s[(mbw+ln)*SP_STRIDE + 32 + lg*8];
      #pragma unroll
      for (int nt = 0; nt < 2; ++nt) {
        const int vr = h*32 + nt*16 + ln;       // output col == vt row
        short8 bv0 = *(const short8*)&vt_s[vr*VT_STRIDE + lg*8];
        short8 bv1 = *(const short8*)&vt_s[vr*VT_STRIDE + 32 + lg*8];
        f32x4 acc = {0.f,0.f,0.f,0.f};
        acc = __builtin_amdgcn_mfma_f32_16x16x32_bf16(ap0, bv0, acc, 0,0,0);
        acc = __builtin_amdgcn_mfma_f32_16x16x32_bf16(ap1, bv1, acc, 0,0,0);
        const int mr = mbw + 4*lg;
        #pragma unroll
        for (int r = 0; r < 4; ++r)
          out[((size_t)b*S49 + mr + r)*D128 + vr] = acc[r];
      }
    }
    __syncthreads();
  }
}

extern "C" void kernel_launch(void* const* d_in, const int* in_sizes, int n_in,
                              void* d_out, int out_size, void* d_ws, size_t ws_size,
                              hipStream_t stream){
  const float* hs  = (const float*)d_in[0];
  const float* msk = (const float*)d_in[1];
  const float* Wq  = (const float*)d_in[2];
  const float* bq  = (const float*)d_in[3];
  const float* Wk  = (const float*)d_in[4];
  const float* bk  = (const float*)d_in[5];
  const float* Wv  = (const float*)d_in[6];
  const float* bv  = (const float*)d_in[7];
  const float* bt  = (const float*)d_in[8];
  unsigned short* wt = (unsigned short*)d_ws;
  float* out = (float*)d_out;
  const int B  = in_sizes[0] / (S49*D128);
  const int nW = in_sizes[1] / (S49*S49);
  prep_wt<<<dim3((3*128*128 + 255)/256), dim3(256), 0, stream>>>(Wq, Wk, Wv, wt);
  swin_attn<<<dim3(B), dim3(256), 0, stream>>>(hs, msk, bq, bk, bv, bt, wt, out, nW);
}

// Round 3
// 142.254 us; speedup vs baseline: 1.5237x; 1.5237x over previous
//
#include <hip/hip_runtime.h>

#define S49 49
#define D128 128
#define NH 4

typedef __attribute__((ext_vector_type(8))) short short8;
typedef __attribute__((ext_vector_type(4))) float f32x4;

#define HS_STRIDE 136   // bf16 elems per row for hs_s/q_s/k_s
#define VT_STRIDE 72    // vt rows (144B)
#define PP_STRIDE 72    // per-wave P buffer rows

__device__ __forceinline__ unsigned short f2b(float x){
  unsigned u = __builtin_bit_cast(unsigned, x);
  return (unsigned short)((u + 0x7fffu + ((u>>16)&1u)) >> 16);   // RNE
}
__device__ __forceinline__ unsigned pack2(float a, float b){
  return (unsigned)f2b(a) | ((unsigned)f2b(b)<<16);
}

// ---- K0: transpose weights to Wt[mat][n][k] bf16 in workspace ----
__global__ void prep_wt(const float* __restrict__ Wq, const float* __restrict__ Wk,
                        const float* __restrict__ Wv, unsigned short* __restrict__ wt){
  int e = blockIdx.x*256 + threadIdx.x;
  if (e >= 3*128*128) return;
  int mat = e >> 14, rem = e & 16383, n = rem >> 7, k = rem & 127;
  const float* W = (mat==0) ? Wq : ((mat==1) ? Wk : Wv);
  wt[e] = f2b(W[k*128 + n]);
}

// ---- K1: combined (mask + rel-pos-bias) table, float4-swizzled for the lane layout ----
// comb4[(((w*NH+h)*49)+i)*16 + ln] = { c(i,ln), c(i,16+ln), c(i,32+ln), c(i,48+ln) }
// c(i,j) = mask[w][i][j] + bias_table[idx(i,j)][h]  for j<49, else -1e30 (self-masking pad)
__global__ void prep_comb(const float* __restrict__ mask, const float* __restrict__ bt,
                          float4* __restrict__ comb4, int nW){
  int e = blockIdx.x*256 + threadIdx.x;
  if (e >= nW*NH*S49*16) return;
  int ln = e & 15; int t = e >> 4;
  int i = t % S49; t /= S49;
  int h = t & (NH-1); int w = t / NH;
  const float* mrow = mask + ((size_t)w*S49 + i)*S49;
  int ri = i/7, ci = i - ri*7;
  float v[4];
  #pragma unroll
  for (int nt = 0; nt < 4; ++nt){
    int j = nt*16 + ln;
    if (j < S49){
      int rj = j/7, cj = j - rj*7;
      int idx = (ri - rj + 6)*13 + (ci - cj + 6);
      v[nt] = mrow[j] + bt[idx*NH + h];
    } else v[nt] = -1e30f;
  }
  float4 o; o.x = v[0]; o.y = v[1]; o.z = v[2]; o.w = v[3];
  comb4[e] = o;
}

// ---- main fused kernel: one block per window, 2 barriers total ----
__global__ __launch_bounds__(256, 2) void swin_attn(
    const float* __restrict__ hs,
    const float* __restrict__ bq, const float* __restrict__ bk,
    const float* __restrict__ bv,
    const float4* __restrict__ comb4,
    const unsigned short* __restrict__ wt, float* __restrict__ out, int nW){

  __shared__ __align__(16) unsigned short hs_s[S49*HS_STRIDE];  // reused as per-wave P buffers
  __shared__ __align__(16) unsigned short q_s [S49*HS_STRIDE];
  __shared__ __align__(16) unsigned short k_s [64*HS_STRIDE];   // rows 49..63 zeroed
  __shared__ __align__(16) unsigned short vt_s[128*VT_STRIDE];  // cols 49..63 zeroed

  const int b = blockIdx.x;
  const int tid = threadIdx.x;
  const int wave = tid >> 6, lane = tid & 63;
  const int lg = lane >> 4, ln = lane & 15;
  unsigned short* pp = hs_s + wave*(16*PP_STRIDE);   // wave-private 16x64(+pad) P tile

  // ---- stage hidden_states f32 -> bf16 LDS ----
  const float* hsb = hs + (size_t)b * (S49*D128);
  #pragma unroll
  for (int it = 0; it < 7; ++it) {
    int u = tid + it*256;                 // 1568 units of 4 f32
    if (u < S49*32) {
      int row = u >> 5, c = u & 31;
      float4 f = *(const float4*)(hsb + row*128 + c*4);
      uint2 o; o.x = pack2(f.x, f.y); o.y = pack2(f.z, f.w);
      *(uint2*)&hs_s[row*HS_STRIDE + c*4] = o;
    }
  }
  // zero K pad rows 49..63 (cols 0..127), as uint writes
  if (tid < 960) {
    int row = 49 + (tid >> 6), c = tid & 63;
    *(unsigned*)&k_s[row*HS_STRIDE + c*2] = 0u;
  }
  // zero vt pad cols 49..63 (K-pad for PV)
  for (int u = tid; u < 128*15; u += 256) {
    int r = u/15, c = 49 + (u - r*15);
    vt_s[r*VT_STRIDE + c] = 0;
  }
  __syncthreads();

  // ---- QKV projections (weights as A-operand; wave owns 32 output cols) ----
  {
    #pragma unroll
    for (int ntl = 0; ntl < 2; ++ntl) {
      const int ntb = wave*32 + ntl*16;
      short8 a[3][4];
      #pragma unroll
      for (int mat = 0; mat < 3; ++mat)
        #pragma unroll
        for (int ks = 0; ks < 4; ++ks)
          a[mat][ks] = *(const short8*)&wt[(mat<<14) + (ntb+ln)*128 + ks*32 + lg*8];
      float4 bias_q = *(const float4*)&bq[ntb + 4*lg];
      float4 bias_k = *(const float4*)&bk[ntb + 4*lg];
      float4 bias_v = *(const float4*)&bv[ntb + 4*lg];
      #pragma unroll
      for (int mt = 0; mt < 4; ++mt) {
        const int mb = (mt<3) ? mt*16 : 33;       // overlapping tiles cover rows 0..48
        short8 bh[4];
        #pragma unroll
        for (int ks = 0; ks < 4; ++ks)
          bh[ks] = *(const short8*)&hs_s[(mb+ln)*HS_STRIDE + ks*32 + lg*8];
        #pragma unroll
        for (int mat = 0; mat < 3; ++mat) {
          f32x4 acc = {0.f,0.f,0.f,0.f};
          #pragma unroll
          for (int ks = 0; ks < 4; ++ks)
            acc = __builtin_amdgcn_mfma_f32_16x16x32_bf16(a[mat][ks], bh[ks], acc, 0,0,0);
          // D is transposed: col(ln)=row m of output, rows(4*lg+r)=output col n
          const int m = mb + ln;
          const int nb = ntb + 4*lg;
          if (mat == 0) {
            uint2 o; o.x = pack2(acc[0]+bias_q.x, acc[1]+bias_q.y);
                     o.y = pack2(acc[2]+bias_q.z, acc[3]+bias_q.w);
            *(uint2*)&q_s[m*HS_STRIDE + nb] = o;
          } else if (mat == 1) {
            uint2 o; o.x = pack2(acc[0]+bias_k.x, acc[1]+bias_k.y);
                     o.y = pack2(acc[2]+bias_k.z, acc[3]+bias_k.w);
            *(uint2*)&k_s[m*HS_STRIDE + nb] = o;
          } else {
            vt_s[(nb+0)*VT_STRIDE + m] = f2b(acc[0]+bias_v.x);
            vt_s[(nb+1)*VT_STRIDE + m] = f2b(acc[1]+bias_v.y);
            vt_s[(nb+2)*VT_STRIDE + m] = f2b(acc[2]+bias_v.z);
            vt_s[(nb+3)*VT_STRIDE + m] = f2b(acc[3]+bias_v.w);
          }
        }
      }
    }
  }
  __syncthreads();
  // ---- attention: NO barriers from here on (P is wave-private, q/k/vt read-only) ----

  const float scale = 0.17677669529663687f;   // 1/sqrt(32)
  const int w = b % nW;
  const int mbw = (wave<3) ? wave*16 : 33;    // wave's q-row tile (overlap benign)

  #pragma unroll 1
  for (int h = 0; h < NH; ++h) {
    // combined bias+mask, float4 per row (issue early; L2-resident)
    float4 cb[4];
    #pragma unroll
    for (int r = 0; r < 4; ++r)
      cb[r] = comb4[((size_t)(w*NH + h)*S49 + mbw + 4*lg + r)*16 + ln];

    // ---- QK^T: 4 non-overlapping j-tiles, scores stay in registers ----
    short8 aq = *(const short8*)&q_s[(mbw+ln)*HS_STRIDE + h*32 + lg*8];
    f32x4 s[4];
    #pragma unroll
    for (int nt = 0; nt < 4; ++nt) {
      short8 kb = *(const short8*)&k_s[(nt*16+ln)*HS_STRIDE + h*32 + lg*8];
      f32x4 z = {0.f,0.f,0.f,0.f};
      s[nt] = __builtin_amdgcn_mfma_f32_16x16x32_bf16(aq, kb, z, 0,0,0);
    }

    // ---- in-register softmax: lane holds rows (mbw+4lg+r), j = nt*16+ln ----
    float x[4][4], m[4], sum[4], inv[4];
    #pragma unroll
    for (int r = 0; r < 4; ++r) {
      x[r][0] = s[0][r]*scale + cb[r].x;
      x[r][1] = s[1][r]*scale + cb[r].y;
      x[r][2] = s[2][r]*scale + cb[r].z;
      x[r][3] = s[3][r]*scale + cb[r].w;
      m[r] = fmaxf(fmaxf(x[r][0], x[r][1]), fmaxf(x[r][2], x[r][3]));
    }
    #pragma unroll
    for (int msk = 1; msk < 16; msk <<= 1) {
      #pragma unroll
      for (int r = 0; r < 4; ++r) m[r] = fmaxf(m[r], __shfl_xor(m[r], msk, 64));
    }
    float e[4][4];
    #pragma unroll
    for (int r = 0; r < 4; ++r) {
      #pragma unroll
      for (int nt = 0; nt < 4; ++nt)
        e[r][nt] = exp2f((x[r][nt] - m[r]) * 1.44269504088896f);
      sum[r] = (e[r][0] + e[r][1]) + (e[r][2] + e[r][3]);
    }
    #pragma unroll
    for (int msk = 1; msk < 16; msk <<= 1) {
      #pragma unroll
      for (int r = 0; r < 4; ++r) sum[r] += __shfl_xor(sum[r], msk, 64);
    }
    #pragma unroll
    for (int r = 0; r < 4; ++r) inv[r] = 1.0f / sum[r];

    // ---- P (unnormalized) -> wave-private LDS in A-fragment layout ----
    #pragma unroll
    for (int r = 0; r < 4; ++r)
      #pragma unroll
      for (int nt = 0; nt < 4; ++nt)
        pp[(4*lg + r)*PP_STRIDE + nt*16 + ln] = f2b(e[r][nt]);

    // ---- P @ V, normalize at store ----
    short8 ap0 = *(const short8*)&pp[ln*PP_STRIDE + lg*8];
    short8 ap1 = *(const short8*)&pp[ln*PP_STRIDE + 32 + lg*8];
    #pragma unroll
    for (int nt = 0; nt < 2; ++nt) {
      const int vr = h*32 + nt*16 + ln;       // output col == vt row
      short8 bv0 = *(const short8*)&vt_s[vr*VT_STRIDE + lg*8];
      short8 bv1 = *(const short8*)&vt_s[vr*VT_STRIDE + 32 + lg*8];
      f32x4 acc = {0.f,0.f,0.f,0.f};
      acc = __builtin_amdgcn_mfma_f32_16x16x32_bf16(ap0, bv0, acc, 0,0,0);
      acc = __builtin_amdgcn_mfma_f32_16x16x32_bf16(ap1, bv1, acc, 0,0,0);
      const int mr = mbw + 4*lg;
      #pragma unroll
      for (int r = 0; r < 4; ++r)
        out[((size_t)b*S49 + mr + r)*D128 + vr] = acc[r]*inv[r];
    }
  }
}

extern "C" void kernel_launch(void* const* d_in, const int* in_sizes, int n_in,
                              void* d_out, int out_size, void* d_ws, size_t ws_size,
                              hipStream_t stream){
  const float* hs  = (const float*)d_in[0];
  const float* msk = (const float*)d_in[1];
  const float* Wq  = (const float*)d_in[2];
  const float* bq  = (const float*)d_in[3];
  const float* Wk  = (const float*)d_in[4];
  const float* bk  = (const float*)d_in[5];
  const float* Wv  = (const float*)d_in[6];
  const float* bv  = (const float*)d_in[7];
  const float* bt  = (const float*)d_in[8];
  unsigned short* wt = (unsigned short*)d_ws;
  float4* comb4 = (float4*)((char*)d_ws + 98304);
  float* out = (float*)d_out;
  const int B  = in_sizes[0] / (S49*D128);
  const int nW = in_sizes[1] / (S49*S49);
  prep_wt<<<dim3((3*128*128 + 255)/256), dim3(256), 0, stream>>>(Wq, Wk, Wv, wt);
  prep_comb<<<dim3((nW*NH*S49*16 + 255)/256), dim3(256), 0, stream>>>(msk, bt, comb4, nW);
  swin_attn<<<dim3(B), dim3(256), 0, stream>>>(hs, bq, bk, bv, comb4, wt, out, nW);
}

// Round 5
// 134.064 us; speedup vs baseline: 1.6167x; 1.0611x over previous
//
#include <hip/hip_runtime.h>
#include <hip/hip_bf16.h>

#define S49 49
#define D128 128
#define NH 4

typedef __attribute__((ext_vector_type(8))) short short8;
typedef __attribute__((ext_vector_type(4))) float f32x4;

__device__ __forceinline__ unsigned short f2b(float x){
  unsigned u = __builtin_bit_cast(unsigned, x);
  return (unsigned short)((u + 0x7fffu + ((u>>16)&1u)) >> 16);   // RNE
}
__device__ __forceinline__ unsigned pk2(float a, float b){
  __hip_bfloat162 h = __float22bfloat162_rn(float2{a, b});      // HW v_cvt_pk_bf16_f32
  unsigned u; __builtin_memcpy(&u, &h, 4);                       // bit_cast rejects non-trivially-copyable
  return u;
}
// XOR-swizzled LDS indexing (ushort units). Row-dependent 16B-granule swizzle:
// conflict-free fragment reads at exact power-of-2 strides (no padding).
__device__ __forceinline__ int swz256i(int row, int col){  // 128-elem (256B) rows
  return row*128 + ((((col>>3) ^ (row&15)) << 3) | (col&7));
}
__device__ __forceinline__ int swz128i(int row, int col){  // 64-elem (128B) rows
  return row*64 + ((((col>>3) ^ (row&7)) << 3) | (col&7));
}

// ---- K0: transpose weights to Wt[mat][n][k] bf16 in workspace ----
__global__ void prep_wt(const float* __restrict__ Wq, const float* __restrict__ Wk,
                        const float* __restrict__ Wv, unsigned short* __restrict__ wt){
  int e = blockIdx.x*256 + threadIdx.x;
  if (e >= 3*128*128) return;
  int mat = e >> 14, rem = e & 16383, n = rem >> 7, k = rem & 127;
  const float* W = (mat==0) ? Wq : ((mat==1) ? Wk : Wv);
  wt[e] = f2b(W[k*128 + n]);
}

// ---- K1: combined (mask + rel-pos-bias) table, float4-swizzled for the lane layout ----
// comb4[(((w*NH+h)*49)+i)*16 + ln] = { c(i,ln), c(i,16+ln), c(i,32+ln), c(i,48+ln) }
// c(i,j) = mask[w][i][j] + bias_table[idx(i,j)][h] for j<49, else -1e30 (pad self-masks)
__global__ void prep_comb(const float* __restrict__ mask, const float* __restrict__ bt,
                          float4* __restrict__ comb4, int nW){
  int e = blockIdx.x*256 + threadIdx.x;
  if (e >= nW*NH*S49*16) return;
  int ln = e & 15; int t = e >> 4;
  int i = t % S49; t /= S49;
  int h = t & (NH-1); int w = t / NH;
  const float* mrow = mask + ((size_t)w*S49 + i)*S49;
  int ri = i/7, ci = i - ri*7;
  float v[4];
  #pragma unroll
  for (int nt = 0; nt < 4; ++nt){
    int j = nt*16 + ln;
    if (j < S49){
      int rj = j/7, cj = j - rj*7;
      int idx = (ri - rj + 6)*13 + (ci - cj + 6);
      v[nt] = mrow[j] + bt[idx*NH + h];
    } else v[nt] = -1e30f;
  }
  float4 o; o.x = v[0]; o.y = v[1]; o.z = v[2]; o.w = v[3];
  comb4[e] = o;
}

// ---- main fused kernel: one block per window, 2 barriers, 3 blocks/CU ----
__global__ __launch_bounds__(256, 3) void swin_attn(
    const float* __restrict__ hs,
    const float* __restrict__ bq, const float* __restrict__ bk,
    const float* __restrict__ bv,
    const float4* __restrict__ comb4,
    const unsigned short* __restrict__ wt, float* __restrict__ out, int nW){

  // 54016 B total: hs/P 12544 | q 12544 | k 12544 | vt 16384
  __shared__ __align__(16) unsigned short lds[27008];
  unsigned short* hs_s = lds;              // 49 x 128, swz256i; reused as per-wave P after proj
  unsigned short* q_s  = lds + 6272;       // 49 x 128, swz256i
  unsigned short* k_s  = lds + 12544;      // 49 x 128, swz256i (tile-3 rows masked in regs)
  unsigned short* vt_s = lds + 18816;      // 128 x 64, swz128i (cols 49..63 zeroed)

  const int b = blockIdx.x;
  const int tid = threadIdx.x;
  const int wave = tid >> 6, lane = tid & 63;
  const int lg = lane >> 4, ln = lane & 15;
  unsigned short* pp = hs_s + wave*1024;   // wave-private 16 x 64, swz128i (local rows)

  // ---- stage hidden_states f32 -> bf16 LDS ----
  const float* hsb = hs + (size_t)b * (S49*D128);
  #pragma unroll
  for (int it = 0; it < 7; ++it) {
    int u = tid + it*256;                  // 1568 units of 4 f32
    if (u < S49*32) {
      int row = u >> 5, c = u & 31;
      float4 f = *(const float4*)(hsb + row*128 + c*4);
      uint2 o; o.x = pk2(f.x, f.y); o.y = pk2(f.z, f.w);
      *(uint2*)&hs_s[swz256i(row, c*4)] = o;
    }
  }
  // zero vt pad cols 49..63 (P is 0 there, but LDS garbage could be NaN: 0*NaN=NaN)
  for (int u = tid; u < 128*15; u += 256) {
    int r = u/15, c = 49 + (u - r*15);
    vt_s[swz128i(r, c)] = 0;
  }
  __syncthreads();

  // ---- QKV projections (weights as A-operand; wave owns 32 output cols) ----
  {
    #pragma unroll
    for (int ntl = 0; ntl < 2; ++ntl) {
      const int ntb = wave*32 + ntl*16;
      short8 a[3][4];
      #pragma unroll
      for (int mat = 0; mat < 3; ++mat)
        #pragma unroll
        for (int ks = 0; ks < 4; ++ks)
          a[mat][ks] = *(const short8*)&wt[(mat<<14) + (ntb+ln)*128 + ks*32 + lg*8];
      float4 bias_q = *(const float4*)&bq[ntb + 4*lg];
      float4 bias_k = *(const float4*)&bk[ntb + 4*lg];
      float4 bias_v = *(const float4*)&bv[ntb + 4*lg];
      #pragma unroll
      for (int mt = 0; mt < 4; ++mt) {
        const int mb = (mt<3) ? mt*16 : 33;       // overlapping tiles cover rows 0..48
        short8 bh[4];
        #pragma unroll
        for (int ks = 0; ks < 4; ++ks)
          bh[ks] = *(const short8*)&hs_s[swz256i(mb+ln, ks*32 + lg*8)];
        #pragma unroll
        for (int mat = 0; mat < 3; ++mat) {
          f32x4 acc = {0.f,0.f,0.f,0.f};
          #pragma unroll
          for (int ks = 0; ks < 4; ++ks)
            acc = __builtin_amdgcn_mfma_f32_16x16x32_bf16(a[mat][ks], bh[ks], acc, 0,0,0);
          // D transposed: col(ln) = hs-row m, rows(4lg+r) = output col n
          const int m = mb + ln;
          const int nb = ntb + 4*lg;
          if (mat == 0) {
            uint2 o; o.x = pk2(acc[0]+bias_q.x, acc[1]+bias_q.y);
                     o.y = pk2(acc[2]+bias_q.z, acc[3]+bias_q.w);
            *(uint2*)&q_s[swz256i(m, nb)] = o;
          } else if (mat == 1) {
            uint2 o; o.x = pk2(acc[0]+bias_k.x, acc[1]+bias_k.y);
                     o.y = pk2(acc[2]+bias_k.z, acc[3]+bias_k.w);
            *(uint2*)&k_s[swz256i(m, nb)] = o;
          } else {
            vt_s[swz128i(nb+0, m)] = f2b(acc[0]+bias_v.x);
            vt_s[swz128i(nb+1, m)] = f2b(acc[1]+bias_v.y);
            vt_s[swz128i(nb+2, m)] = f2b(acc[2]+bias_v.z);
            vt_s[swz128i(nb+3, m)] = f2b(acc[3]+bias_v.w);
          }
        }
      }
    }
  }
  __syncthreads();
  // ---- attention: NO barriers (P wave-private; q/k/vt read-only; pp aliases dead hs) ----

  const float scale = 0.17677669529663687f;   // 1/sqrt(32)
  const int w = b % nW;
  const int mbw = (wave<3) ? wave*16 : 33;    // wave's q-row tile (overlap rows recompute identically)

  #pragma unroll
  for (int h = 0; h < NH; ++h) {
    float4 cb[4];
    #pragma unroll
    for (int r = 0; r < 4; ++r)
      cb[r] = comb4[((size_t)(w*NH + h)*S49 + mbw + 4*lg + r)*16 + ln];

    // ---- QK^T: tiles {0,16,32,48}; scores stay in registers ----
    short8 aq = *(const short8*)&q_s[swz256i(mbw+ln, h*32 + lg*8)];
    short8 kb[4];
    #pragma unroll
    for (int nt = 0; nt < 4; ++nt)
      kb[nt] = *(const short8*)&k_s[swz256i(nt*16+ln, h*32 + lg*8)];  // nt=3 rows 49..63 read in-LDS garbage
    if (ln != 0) kb[3] = short8{0,0,0,0,0,0,0,0};                     // mask: only row 48 is real
    f32x4 s[4];
    __builtin_amdgcn_s_setprio(1);
    #pragma unroll
    for (int nt = 0; nt < 4; ++nt) {
      f32x4 z = {0.f,0.f,0.f,0.f};
      s[nt] = __builtin_amdgcn_mfma_f32_16x16x32_bf16(aq, kb[nt], z, 0,0,0);
    }
    __builtin_amdgcn_s_setprio(0);

    // ---- in-register softmax: lane holds rows (mbw+4lg+r), j = nt*16+ln ----
    float x[4][4], m[4], sum[4], inv[4];
    #pragma unroll
    for (int r = 0; r < 4; ++r) {
      x[r][0] = s[0][r]*scale + cb[r].x;
      x[r][1] = s[1][r]*scale + cb[r].y;
      x[r][2] = s[2][r]*scale + cb[r].z;
      x[r][3] = s[3][r]*scale + cb[r].w;
      m[r] = fmaxf(fmaxf(x[r][0], x[r][1]), fmaxf(x[r][2], x[r][3]));
    }
    #pragma unroll
    for (int msk = 1; msk < 16; msk <<= 1) {
      #pragma unroll
      for (int r = 0; r < 4; ++r) m[r] = fmaxf(m[r], __shfl_xor(m[r], msk, 64));
    }
    float e[4][4];
    #pragma unroll
    for (int r = 0; r < 4; ++r) {
      #pragma unroll
      for (int nt = 0; nt < 4; ++nt)
        e[r][nt] = exp2f((x[r][nt] - m[r]) * 1.44269504088896f);
      sum[r] = (e[r][0] + e[r][1]) + (e[r][2] + e[r][3]);
    }
    #pragma unroll
    for (int msk = 1; msk < 16; msk <<= 1) {
      #pragma unroll
      for (int r = 0; r < 4; ++r) sum[r] += __shfl_xor(sum[r], msk, 64);
    }
    #pragma unroll
    for (int r = 0; r < 4; ++r) inv[r] = 1.0f / sum[r];

    // ---- P (unnormalized) -> wave-private LDS in A-fragment layout ----
    #pragma unroll
    for (int r = 0; r < 4; ++r)
      #pragma unroll
      for (int nt = 0; nt < 4; ++nt)
        pp[swz128i(4*lg + r, nt*16 + ln)] = f2b(e[r][nt]);

    // ---- P @ V, normalize at store ----
    short8 ap0 = *(const short8*)&pp[swz128i(ln, lg*8)];
    short8 ap1 = *(const short8*)&pp[swz128i(ln, 32 + lg*8)];
    #pragma unroll
    for (int nt = 0; nt < 2; ++nt) {
      const int vr = h*32 + nt*16 + ln;       // output col == vt row
      short8 bv0 = *(const short8*)&vt_s[swz128i(vr, lg*8)];
      short8 bv1 = *(const short8*)&vt_s[swz128i(vr, 32 + lg*8)];
      f32x4 acc = {0.f,0.f,0.f,0.f};
      __builtin_amdgcn_s_setprio(1);
      acc = __builtin_amdgcn_mfma_f32_16x16x32_bf16(ap0, bv0, acc, 0,0,0);
      acc = __builtin_amdgcn_mfma_f32_16x16x32_bf16(ap1, bv1, acc, 0,0,0);
      __builtin_amdgcn_s_setprio(0);
      const int mr = mbw + 4*lg;
      #pragma unroll
      for (int r = 0; r < 4; ++r)
        out[((size_t)b*S49 + mr + r)*D128 + vr] = acc[r]*inv[r];
    }
  }
}

extern "C" void kernel_launch(void* const* d_in, const int* in_sizes, int n_in,
                              void* d_out, int out_size, void* d_ws, size_t ws_size,
                              hipStream_t stream){
  const float* hs  = (const float*)d_in[0];
  const float* msk = (const float*)d_in[1];
  const float* Wq  = (const float*)d_in[2];
  const float* bq  = (const float*)d_in[3];
  const float* Wk  = (const float*)d_in[4];
  const float* bk  = (const float*)d_in[5];
  const float* Wv  = (const float*)d_in[6];
  const float* bv  = (const float*)d_in[7];
  const float* bt  = (const float*)d_in[8];
  unsigned short* wt = (unsigned short*)d_ws;
  float4* comb4 = (float4*)((char*)d_ws + 98304);
  float* out = (float*)d_out;
  const int B  = in_sizes[0] / (S49*D128);
  const int nW = in_sizes[1] / (S49*S49);
  prep_wt<<<dim3((3*128*128 + 255)/256), dim3(256), 0, stream>>>(Wq, Wk, Wv, wt);
  prep_comb<<<dim3((nW*NH*S49*16 + 255)/256), dim3(256), 0, stream>>>(msk, bt, comb4, nW);
  swin_attn<<<dim3(B), dim3(256), 0, stream>>>(hs, bq, bk, bv, comb4, wt, out, nW);
}

// Round 6
// 102.107 us; speedup vs baseline: 2.1227x; 1.3130x over previous
//
#include <hip/hip_runtime.h>
#include <hip/hip_bf16.h>

#define S49 49
#define D128 128
#define NH 4

typedef __attribute__((ext_vector_type(8))) short short8;
typedef __attribute__((ext_vector_type(4))) float f32x4;

__device__ __forceinline__ unsigned short f2b(float x){
  unsigned u = __builtin_bit_cast(unsigned, x);
  return (unsigned short)((u + 0x7fffu + ((u>>16)&1u)) >> 16);   // RNE
}
__device__ __forceinline__ unsigned pk2(float a, float b){
  __hip_bfloat162 h = __float22bfloat162_rn(float2{a, b});      // HW v_cvt_pk_bf16_f32
  unsigned u; __builtin_memcpy(&u, &h, 4);
  return u;
}
// XOR-swizzled LDS indexing (ushort units), 16B granule: conflict-free
// fragment reads at power-of-2 strides, no padding.
__device__ __forceinline__ int swz256i(int row, int col){  // 128-elem (256B) rows
  return row*128 + ((((col>>3) ^ (row&15)) << 3) | (col&7));
}
__device__ __forceinline__ int swz128i(int row, int col){  // 64-elem (128B) rows
  return row*64 + ((((col>>3) ^ (row&7)) << 3) | (col&7));
}

// ---- K0: transpose weights to Wt[mat][n][k] bf16 in workspace ----
__global__ void prep_wt(const float* __restrict__ Wq, const float* __restrict__ Wk,
                        const float* __restrict__ Wv, unsigned short* __restrict__ wt){
  int e = blockIdx.x*256 + threadIdx.x;
  if (e >= 3*128*128) return;
  int mat = e >> 14, rem = e & 16383, n = rem >> 7, k = rem & 127;
  const float* W = (mat==0) ? Wq : ((mat==1) ? Wk : Wv);
  wt[e] = f2b(W[k*128 + n]);
}

// ---- K1: combined (mask + rel-pos-bias) table, PRE-SCALED by log2(e), float4-swizzled ----
// comb4[(((w*NH+h)*49)+i)*16 + ln] = { c(i,ln), c(i,16+ln), c(i,32+ln), c(i,48+ln) } * log2e
// pad (j>=49) = -1e30 so exp2 -> 0 exactly.
__global__ void prep_comb(const float* __restrict__ mask, const float* __restrict__ bt,
                          float4* __restrict__ comb4, int nW){
  int e = blockIdx.x*256 + threadIdx.x;
  if (e >= nW*NH*S49*16) return;
  int ln = e & 15; int t = e >> 4;
  int i = t % S49; t /= S49;
  int h = t & (NH-1); int w = t / NH;
  const float* mrow = mask + ((size_t)w*S49 + i)*S49;
  int ri = i/7, ci = i - ri*7;
  const float L2E = 1.4426950408889634f;
  float v[4];
  #pragma unroll
  for (int nt = 0; nt < 4; ++nt){
    int j = nt*16 + ln;
    if (j < S49){
      int rj = j/7, cj = j - rj*7;
      int idx = (ri - rj + 6)*13 + (ci - cj + 6);
      v[nt] = (mrow[j] + bt[idx*NH + h]) * L2E;
    } else v[nt] = -1e30f;
  }
  float4 o; o.x = v[0]; o.y = v[1]; o.z = v[2]; o.w = v[3];
  comb4[e] = o;
}

// ---- main fused kernel: one block (8 waves) per window, 2 barriers ----
// wave = (row-tile rt = wave&3, head-pair hp = wave>>2)
__global__ __launch_bounds__(512, 4) void swin_attn(
    const float* __restrict__ hs,
    const float* __restrict__ bq, const float* __restrict__ bk,
    const float* __restrict__ bv,
    const float4* __restrict__ comb4,
    const unsigned short* __restrict__ wt, float* __restrict__ out, int nW){

  // 58112 B: hs/P 12544 | q 12544 | k 12544 | vt 16384 | pext 4096
  __shared__ __align__(16) unsigned short lds[29056];
  unsigned short* hs_s = lds;              // 49 x 128, swz256i; dead after proj -> P tiles waves 0..5
  unsigned short* q_s  = lds + 6272;       // 49 x 128, swz256i
  unsigned short* k_s  = lds + 12544;      // 49 x 128, swz256i (rows 49..63 of tile 3 reg-masked)
  unsigned short* vt_s = lds + 18816;      // 128 x 64, swz128i (cols 49..63 zeroed)
  unsigned short* pext = lds + 27008;      // P tiles for waves 6,7

  const int b = blockIdx.x;
  const int tid = threadIdx.x;
  const int wave = tid >> 6, lane = tid & 63;
  const int lg = lane >> 4, ln = lane & 15;
  unsigned short* pp = (wave < 6) ? (hs_s + wave*1024) : (pext + (wave-6)*1024);  // 16x64 swz128i

  // ---- stage hidden_states f32 -> bf16 LDS ----
  const float* hsb = hs + (size_t)b * (S49*D128);
  #pragma unroll
  for (int it = 0; it < 4; ++it) {
    int u = tid + it*512;                  // 1568 units of 4 f32
    if (u < S49*32) {
      int row = u >> 5, c = u & 31;
      float4 f = *(const float4*)(hsb + row*128 + c*4);
      uint2 o; o.x = pk2(f.x, f.y); o.y = pk2(f.z, f.w);
      *(uint2*)&hs_s[swz256i(row, c*4)] = o;
    }
  }
  // zero vt pad cols 49..63 (avoid NaN from garbage: 0*NaN=NaN)
  #pragma unroll
  for (int it = 0; it < 4; ++it) {
    int u = tid + it*512;
    if (u < 128*15) {
      int r = u/15, c = 49 + (u - r*15);
      vt_s[swz128i(r, c)] = 0;
    }
  }
  __syncthreads();

  // ---- QKV projection: wave owns 16 output cols of EACH of the 3 matrices ----
  {
    const int ntb = wave*16;
    short8 a[3][4];
    #pragma unroll
    for (int mat = 0; mat < 3; ++mat)
      #pragma unroll
      for (int ks = 0; ks < 4; ++ks)
        a[mat][ks] = *(const short8*)&wt[(mat<<14) + (ntb+ln)*128 + ks*32 + lg*8];
    float4 bias_q = *(const float4*)&bq[ntb + 4*lg];
    float4 bias_k = *(const float4*)&bk[ntb + 4*lg];
    float4 bias_v = *(const float4*)&bv[ntb + 4*lg];
    #pragma unroll
    for (int mt = 0; mt < 4; ++mt) {
      const int mb = (mt<3) ? mt*16 : 33;        // overlapping tiles cover rows 0..48
      short8 bh[4];
      #pragma unroll
      for (int ks = 0; ks < 4; ++ks)
        bh[ks] = *(const short8*)&hs_s[swz256i(mb+ln, ks*32 + lg*8)];
      #pragma unroll
      for (int mat = 0; mat < 3; ++mat) {
        f32x4 acc = {0.f,0.f,0.f,0.f};
        #pragma unroll
        for (int ks = 0; ks < 4; ++ks)
          acc = __builtin_amdgcn_mfma_f32_16x16x32_bf16(a[mat][ks], bh[ks], acc, 0,0,0);
        // D transposed: col(ln) = token row m, rows(4lg+r) = output col n
        const int m = mb + ln;
        const int nb = ntb + 4*lg;
        if (mat == 0) {
          uint2 o; o.x = pk2(acc[0]+bias_q.x, acc[1]+bias_q.y);
                   o.y = pk2(acc[2]+bias_q.z, acc[3]+bias_q.w);
          *(uint2*)&q_s[swz256i(m, nb)] = o;
        } else if (mat == 1) {
          uint2 o; o.x = pk2(acc[0]+bias_k.x, acc[1]+bias_k.y);
                   o.y = pk2(acc[2]+bias_k.z, acc[3]+bias_k.w);
          *(uint2*)&k_s[swz256i(m, nb)] = o;
        } else {
          vt_s[swz128i(nb+0, m)] = f2b(acc[0]+bias_v.x);
          vt_s[swz128i(nb+1, m)] = f2b(acc[1]+bias_v.y);
          vt_s[swz128i(nb+2, m)] = f2b(acc[2]+bias_v.z);
          vt_s[swz128i(nb+3, m)] = f2b(acc[3]+bias_v.w);
        }
      }
    }
  }
  __syncthreads();
  // ---- attention: NO barriers (P wave-private; q/k/vt read-only; pp aliases dead hs) ----

  const float C1 = 0.17677669529663687f * 1.4426950408889634f;  // scale * log2e
  const int w = b % nW;
  const int rt = wave & 3, hp = wave >> 1 >> 1;   // hp = wave>>2
  const int mbw = (rt<3) ? rt*16 : 33;            // overlap rows recompute identical values
  const short8 ones = {16256,16256,16256,16256,16256,16256,16256,16256};  // bf16 1.0

  #pragma unroll
  for (int hh = 0; hh < 2; ++hh) {
    const int h = hp*2 + hh;
    float4 cb[4];
    #pragma unroll
    for (int r = 0; r < 4; ++r)
      cb[r] = comb4[((size_t)(w*NH + h)*S49 + mbw + 4*lg + r)*16 + ln];

    // ---- QK^T: tiles {0,16,32,48}; scores stay in registers ----
    short8 aq = *(const short8*)&q_s[swz256i(mbw+ln, h*32 + lg*8)];
    short8 kb[4];
    #pragma unroll
    for (int nt = 0; nt < 4; ++nt)
      kb[nt] = *(const short8*)&k_s[swz256i(nt*16+ln, h*32 + lg*8)];  // nt=3: rows 49.. are garbage
    if (ln != 0) kb[3] = short8{0,0,0,0,0,0,0,0};                     // zero B cols 49..63 (no NaN)
    f32x4 s[4];
    __builtin_amdgcn_s_setprio(1);
    #pragma unroll
    for (int nt = 0; nt < 4; ++nt) {
      f32x4 z = {0.f,0.f,0.f,0.f};
      s[nt] = __builtin_amdgcn_mfma_f32_16x16x32_bf16(aq, kb[nt], z, 0,0,0);
    }
    __builtin_amdgcn_s_setprio(0);

    // ---- max-free softmax numerator; pads produce exactly 0 ----
    // lane holds rows (mbw+4lg+r), j = nt*16+ln
    #pragma unroll
    for (int r = 0; r < 4; ++r) {
      float cbv[4] = {cb[r].x, cb[r].y, cb[r].z, cb[r].w};
      #pragma unroll
      for (int nt = 0; nt < 4; ++nt) {
        float e = exp2f(fmaf(s[nt][r], C1, cbv[nt]));
        pp[swz128i(4*lg + r, nt*16 + ln)] = f2b(e);
      }
    }

    // ---- row-sum via P @ ones, then P @ V; normalize at store ----
    short8 ap0 = *(const short8*)&pp[swz128i(ln, lg*8)];
    short8 ap1 = *(const short8*)&pp[swz128i(ln, 32 + lg*8)];
    f32x4 sacc = {0.f,0.f,0.f,0.f};
    __builtin_amdgcn_s_setprio(1);
    sacc = __builtin_amdgcn_mfma_f32_16x16x32_bf16(ap0, ones, sacc, 0,0,0);
    sacc = __builtin_amdgcn_mfma_f32_16x16x32_bf16(ap1, ones, sacc, 0,0,0);
    __builtin_amdgcn_s_setprio(0);
    float inv[4];
    #pragma unroll
    for (int r = 0; r < 4; ++r) inv[r] = __builtin_amdgcn_rcpf(sacc[r]);

    #pragma unroll
    for (int nt = 0; nt < 2; ++nt) {
      const int vr = h*32 + nt*16 + ln;       // output col == vt row
      short8 bv0 = *(const short8*)&vt_s[swz128i(vr, lg*8)];
      short8 bv1 = *(const short8*)&vt_s[swz128i(vr, 32 + lg*8)];
      f32x4 acc = {0.f,0.f,0.f,0.f};
      __builtin_amdgcn_s_setprio(1);
      acc = __builtin_amdgcn_mfma_f32_16x16x32_bf16(ap0, bv0, acc, 0,0,0);
      acc = __builtin_amdgcn_mfma_f32_16x16x32_bf16(ap1, bv1, acc, 0,0,0);
      __builtin_amdgcn_s_setprio(0);
      const int mr = mbw + 4*lg;
      #pragma unroll
      for (int r = 0; r < 4; ++r)
        out[((size_t)b*S49 + mr + r)*D128 + vr] = acc[r]*inv[r];
    }
  }
}

extern "C" void kernel_launch(void* const* d_in, const int* in_sizes, int n_in,
                              void* d_out, int out_size, void* d_ws, size_t ws_size,
                              hipStream_t stream){
  const float* hs  = (const float*)d_in[0];
  const float* msk = (const float*)d_in[1];
  const float* Wq  = (const float*)d_in[2];
  const float* bq  = (const float*)d_in[3];
  const float* Wk  = (const float*)d_in[4];
  const float* bk  = (const float*)d_in[5];
  const float* Wv  = (const float*)d_in[6];
  const float* bv  = (const float*)d_in[7];
  const float* bt  = (const float*)d_in[8];
  unsigned short* wt = (unsigned short*)d_ws;
  float4* comb4 = (float4*)((char*)d_ws + 98304);
  float* out = (float*)d_out;
  const int B  = in_sizes[0] / (S49*D128);
  const int nW = in_sizes[1] / (S49*S49);
  prep_wt<<<dim3((3*128*128 + 255)/256), dim3(256), 0, stream>>>(Wq, Wk, Wv, wt);
  prep_comb<<<dim3((nW*NH*S49*16 + 255)/256), dim3(256), 0, stream>>>(msk, bt, comb4, nW);
  swin_attn<<<dim3(B), dim3(512), 0, stream>>>(hs, bq, bk, bv, comb4, wt, out, nW);
}